// Round 10
// baseline (23.508 us; speedup 1.0000x reference)
//
#include <hip/hip_runtime.h>
#include <math.h>

// Problem constants (from reference setup_inputs): B=32, N=256, D=32.
#define BB 32
#define NN 256
#define DD 32
#define TPB 256                  // 4 waves: wave = one j-subchunk of 8
#define RPT 4                    // A-rows per thread: rows {l,l+64,l+128,l+192}
#define SPLIT 8                  // j-chunks per (batch,type)
#define JCHUNK (NN / SPLIT)      // 32 j's staged per block
#define SJ (JCHUNK / 4)          // 8 j's per wave
#define NPART (BB * 3 * SPLIT)   // 768 blocks / partials

__device__ __forceinline__ void pin4(float4& v) {
    asm volatile("" : "+v"(v.x), "+v"(v.y), "+v"(v.z), "+v"(v.w));
}

// type 0: (x,x) +1 | type 1: (y,y) +1 | type 2: (x,y) -2
// R9->R10: RPT 2->4 halves LDS-pipe instructions again (64 ds_read_b128
// per wave). __launch_bounds__(256,2) gives a 256-VGPR cap — enough for
// the 128-VGPR A-fragment (R9 proved this regime allocates honestly).
__global__ __launch_bounds__(TPB, 2) void mmd_partial(
    const float* __restrict__ x, const float* __restrict__ y,
    const float* __restrict__ w, float* __restrict__ partials) {
    const int blk  = blockIdx.x;
    const int s    = blk & (SPLIT - 1);
    const int bt   = blk / SPLIT;
    const int type = bt % 3;
    const int b    = bt / 3;
    const int tid  = threadIdx.x;
    const int wave = tid >> 6;       // j-subchunk owner
    const int lane = tid & 63;

    const float* Arow_base = (type == 1) ? y : x;   // rows (i)
    const float* Bcol_base = (type == 0) ? x : y;   // cols (j)

    // 4 A-rows per thread in registers (128 VGPRs), pinned against
    // sinking/remat of the loads into the j-loop.
    float4 a[RPT][DD / 4];
    #pragma unroll
    for (int r = 0; r < RPT; ++r) {
        const int i = r * 64 + lane;
        const float4* ar =
            (const float4*)(Arow_base + ((size_t)b * NN + i) * DD);
        #pragma unroll
        for (int k = 0; k < DD / 4; ++k) a[r][k] = ar[k];
    }
    #pragma unroll
    for (int r = 0; r < RPT; ++r)
        #pragma unroll
        for (int k = 0; k < DD / 4; ++k) pin4(a[r][k]);

    // |a|^2 with the 4-chain structure (identical to dot & b2 chains so the
    // xx/yy diagonal cancels to exact 0 before the clamp).
    float a2[RPT];
    #pragma unroll
    for (int r = 0; r < RPT; ++r) {
        float c0 = 0.f, c1 = 0.f, c2 = 0.f, c3 = 0.f;
        #pragma unroll
        for (int k = 0; k < DD / 4; ++k) {
            float4 v = a[r][k];
            c0 = fmaf(v.x, v.x, c0);
            c1 = fmaf(v.y, v.y, c1);
            c2 = fmaf(v.z, v.z, c2);
            c3 = fmaf(v.w, v.w, c3);
        }
        a2[r] = (c0 + c1) + (c2 + c3);
    }

    // Stage 32 B-rows (4 KB) in LDS: exactly 1 float4 store per thread.
    __shared__ float4 bs4[JCHUNK * (DD / 4)];
    __shared__ float b2s[JCHUNK];
    {
        const float4* bb =
            (const float4*)(Bcol_base + ((size_t)b * NN + s * JCHUNK) * DD);
        bs4[tid] = bb[tid];
    }
    __syncthreads();
    if (tid < JCHUNK) {
        float c0 = 0.f, c1 = 0.f, c2 = 0.f, c3 = 0.f;
        #pragma unroll
        for (int k = 0; k < DD / 4; ++k) {
            float4 v = bs4[tid * (DD / 4) + k];
            c0 = fmaf(v.x, v.x, c0);
            c1 = fmaf(v.y, v.y, c1);
            c2 = fmaf(v.z, v.z, c2);
            c3 = fmaf(v.w, v.w, c3);
        }
        b2s[tid] = (c0 + c1) + (c2 + c3);
    }
    __syncthreads();

    const float negw = -w[b] * (1.0f / (float)DD);

    float acc[RPT] = {0.f, 0.f, 0.f, 0.f};
    #pragma unroll 2
    for (int j = 0; j < SJ; ++j) {
        const int jg = wave * SJ + j;
        const float b2 = b2s[jg];
        float c[RPT][4];
        #pragma unroll
        for (int r = 0; r < RPT; ++r)
            c[r][0] = c[r][1] = c[r][2] = c[r][3] = 0.f;
        #pragma unroll
        for (int k = 0; k < DD / 4; ++k) {
            const float4 bv = bs4[jg * (DD / 4) + k];  // uniform -> broadcast
            #pragma unroll
            for (int r = 0; r < RPT; ++r) {
                c[r][0] = fmaf(a[r][k].x, bv.x, c[r][0]);
                c[r][1] = fmaf(a[r][k].y, bv.y, c[r][1]);
                c[r][2] = fmaf(a[r][k].z, bv.z, c[r][2]);
                c[r][3] = fmaf(a[r][k].w, bv.w, c[r][3]);
            }
        }
        #pragma unroll
        for (int r = 0; r < RPT; ++r) {
            const float dot = (c[r][0] + c[r][1]) + (c[r][2] + c[r][3]);
            float sq = fmaf(-2.0f, dot, a2[r] + b2);
            sq = fmaxf(sq, 1e-8f);   // folds norm clamp: sqrt(1e-8) = 1e-4
            acc[r] += __expf(negw * __builtin_amdgcn_sqrtf(sq));
        }
    }

    // Deterministic block reduction: wave shuffle + fixed-order cross-wave.
    float tsum = (acc[0] + acc[1]) + (acc[2] + acc[3]);
    #pragma unroll
    for (int off = 32; off > 0; off >>= 1) tsum += __shfl_down(tsum, off, 64);
    __shared__ float red[TPB / 64];
    if (lane == 0) red[wave] = tsum;
    __syncthreads();
    if (tid == 0) {
        const float bsum = (red[0] + red[1]) + (red[2] + red[3]);
        const float weight = (type == 2) ? -2.0f : 1.0f;
        const float scale  = weight / ((float)NN * (float)NN * (float)BB);
        partials[blk] = bsum * scale;
    }
}

// Final deterministic reduction of NPART partials in double.
__global__ __launch_bounds__(256) void mmd_reduce(
    const float* __restrict__ partials, float* __restrict__ out) {
    double acc = 0.0;
    #pragma unroll
    for (int t = 0; t < NPART / 256; ++t)
        acc += (double)partials[threadIdx.x + t * 256];
    #pragma unroll
    for (int off = 32; off > 0; off >>= 1) acc += __shfl_down(acc, off, 64);
    __shared__ double red[4];
    if ((threadIdx.x & 63) == 0) red[threadIdx.x >> 6] = acc;
    __syncthreads();
    if (threadIdx.x == 0)
        out[0] = (float)((red[0] + red[1]) + (red[2] + red[3]));
}

extern "C" void kernel_launch(void* const* d_in, const int* in_sizes, int n_in,
                              void* d_out, int out_size, void* d_ws, size_t ws_size,
                              hipStream_t stream) {
    const float* x = (const float*)d_in[0];
    const float* y = (const float*)d_in[1];
    const float* w = (const float*)d_in[2];
    float* out = (float*)d_out;
    float* partials = (float*)d_ws;  // NPART floats

    mmd_partial<<<NPART, TPB, 0, stream>>>(x, y, w, partials);
    mmd_reduce<<<1, 256, 0, stream>>>(partials, out);
}